// Round 10
// baseline (148.968 us; speedup 1.0000x reference)
//
#include <hip/hip_runtime.h>
#include <hip/hip_bf16.h>
#include <math.h>

// FFM: B=32768, n=512, f=30, k=40
// inter[b] = X[b]^T W X[b],  W = 0.5*(C - diag(C)), C symmetric
// out = sigmoid(X@w1 + b + inter)
//
// R10: LDS-traffic cut + register-B from a PRE-TILED W image.
//  - Wave tile 64 rows x 128 cols (cb merged): As read ONCE (1 KB/lane).
//  - retile_w writes W in per-lane fragment order: img[t][wave][lane][ni*8]
//    -> each lane's 8 b-frags per K32 slab are 128 CONTIGUOUS bytes; the
//    K-loop streams them with dense global_load_dwordx4 (no LDS, no barriers,
//    no 1KB-stride scatter).
//  - LDS = As 64 KB + part 1 KB -> 2 blocks/CU, 8 waves/CU.
//  - Epilogue uses bf16 x from As (keeps FETCH at ~36 MB).

#define N_FEAT 512
#define FK 1200
#define KDIM 40
#define B_ROWS 32768
#define BM 64

typedef __attribute__((ext_vector_type(8))) short short8;
typedef __attribute__((ext_vector_type(4))) float f32x4;

__device__ __forceinline__ unsigned short bf16_rne(float f) {
    union { float f; unsigned int u; } c; c.f = f;
    unsigned int u = c.u;
    u += 0x7fffu + ((u >> 16) & 1u);
    return (unsigned short)(u >> 16);
}

__device__ __forceinline__ float bf16_to_f(unsigned short h) {
    union { unsigned int u; float f; } c;
    c.u = ((unsigned int)h) << 16;
    return c.f;
}

// ---------------- Kernel 0: transpose v (512 x 1200) -> vT (1200 x 512) ----------------
__global__ __launch_bounds__(256) void transpose_v(const float* __restrict__ v,
                                                   float* __restrict__ vT) {
    const int c = blockIdx.x;           // 0..1199
    const int i0 = threadIdx.x;
    vT[(size_t)c * N_FEAT + i0]       = v[(size_t)i0 * FK + c];
    vT[(size_t)c * N_FEAT + i0 + 256] = v[(size_t)(i0 + 256) * FK + c];
}

// ---------------- Kernel 1: build W16 (512x512 bf16), coalesced ----------------
__global__ __launch_bounds__(256) void build_w16(const float* __restrict__ v,
                                                 const float* __restrict__ vT,
                                                 const int* __restrict__ f2f,
                                                 unsigned short* __restrict__ W16) {
    __shared__ float vi[FK];
    const int tid = threadIdx.x;
    const int i   = blockIdx.x;         // 0..511

    for (int c = tid; c < FK; c += 256)
        vi[c] = v[(size_t)i * FK + c];
    const int fi = f2f[i];
    const int j0 = tid;
    const int j1 = tid + 256;
    const int fj0 = f2f[j0];
    const int fj1 = f2f[j1];
    __syncthreads();

    const float* base = vT + (size_t)fi * KDIM * N_FEAT;
    float acc0 = 0.f, acc1 = 0.f;
#pragma unroll
    for (int q = 0; q < KDIM; ++q) {
        const float c0 = base[q * N_FEAT + j0];
        const float c1 = base[q * N_FEAT + j1];
        acc0 = fmaf(vi[fj0 * KDIM + q], c0, acc0);
        acc1 = fmaf(vi[fj1 * KDIM + q], c1, acc1);
    }
    W16[(size_t)i * N_FEAT + j0] = (i == j0) ? (unsigned short)0 : bf16_rne(0.5f * acc0);
    W16[(size_t)i * N_FEAT + j1] = (i == j1) ? (unsigned short)0 : bf16_rne(0.5f * acc1);
}

// ---------------- Kernel 1b: re-tile W16 into per-lane fragment order ----------------
// chunk c (16B): c = ((t*4 + w)*64 + lane)*8 + ni
//   col = w*128 + ni*16 + (lane&15),  k = t*32 + (lane>>4)*8
__global__ __launch_bounds__(256) void retile_w(const unsigned short* __restrict__ W16,
                                                unsigned short* __restrict__ img) {
    const int c   = blockIdx.x * 256 + threadIdx.x;   // 0..32767
    const int ni  = c & 7;
    const int l   = (c >> 3) & 63;
    const int w   = (c >> 9) & 3;
    const int t   = c >> 11;                          // 0..15
    const int col = w * 128 + ni * 16 + (l & 15);
    const int k   = t * 32 + (l >> 4) * 8;
    *(short8*)(img + (size_t)c * 8) =
        *(const short8*)(W16 + (size_t)col * N_FEAT + k);
}

// ---------------- Kernel 2: fused GEMM + quadratic-form epilogue ----------------
// grid: 512 blocks x 256 threads (4 waves). Wave w: 64 rows x 128 cols
// (cols = w*128). B frags stream from img (dense per-lane 128 B); no K-loop
// barriers, no B LDS.
__global__ __launch_bounds__(256, 2) void ffm_fused(const float* __restrict__ X,
                                                    const unsigned short* __restrict__ img,
                                                    const float* __restrict__ w1,
                                                    const float* __restrict__ bvec,
                                                    float* __restrict__ out) {
    __shared__ __align__(16) unsigned short As[BM * N_FEAT];   // 64 KB, swizzled
    __shared__ float part[4][BM];                               // 1 KB

    const int tid  = threadIdx.x;
    const int lane = tid & 63;
    const int wave = tid >> 6;
    const int quad = lane >> 4;
    const int l16  = lane & 15;
    const int aswz = l16 & 7;

    const size_t row0 = (size_t)blockIdx.x * BM;

    // ---- Phase A: stage As = bf16(X[row0:+64][0:512]), XOR-swizzled ----
    {
        const float4* X4 = (const float4*)(X + row0 * N_FEAT);
#pragma unroll
        for (int u = 0; u < 16; ++u) {
            const int r  = u * 4 + wave;    // wave-uniform row
            const int cc = lane;            // 16B chunk in row
            float4 f0 = X4[r * 128 + cc * 2];
            float4 f1 = X4[r * 128 + cc * 2 + 1];
            union { unsigned short us[8]; short8 v; } pk;
            pk.us[0] = bf16_rne(f0.x);
            pk.us[1] = bf16_rne(f0.y);
            pk.us[2] = bf16_rne(f0.z);
            pk.us[3] = bf16_rne(f0.w);
            pk.us[4] = bf16_rne(f1.x);
            pk.us[5] = bf16_rne(f1.y);
            pk.us[6] = bf16_rne(f1.z);
            pk.us[7] = bf16_rne(f1.w);
            *(short8*)(As + r * N_FEAT + ((cc ^ (r & 7)) << 3)) = pk.v;
        }
    }
    __syncthreads();   // As ready; no further barriers until reduction

    f32x4 acc[4][8];
#pragma unroll
    for (int mi = 0; mi < 4; ++mi)
#pragma unroll
        for (int ni = 0; ni < 8; ++ni)
            acc[mi][ni] = (f32x4){0.f, 0.f, 0.f, 0.f};

    // lane's B stream base: img + t*16384 + wave*4096 + lane*64 (elems)
    const unsigned short* bpl = img + (size_t)wave * 4096 + (size_t)lane * 64;

#pragma unroll 1
    for (int t = 0; t < 16; ++t) {
        const unsigned short* bt = bpl + t * 16384;
        short8 b[8];
#pragma unroll
        for (int ni = 0; ni < 8; ++ni)
            b[ni] = *(const short8*)(bt + ni * 8);     // 128 B contiguous/lane

        short8 a[4];
        const int kc  = t * 4 + quad;
        const int off = (kc ^ aswz) << 3;
#pragma unroll
        for (int mi = 0; mi < 4; ++mi)
            a[mi] = *(const short8*)(As + (mi * 16 + l16) * N_FEAT + off);

#pragma unroll
        for (int mi = 0; mi < 4; ++mi)
#pragma unroll
            for (int ni = 0; ni < 8; ++ni)
                acc[mi][ni] = __builtin_amdgcn_mfma_f32_16x16x32_bf16(
                    a[mi], b[ni], acc[mi][ni], 0, 0, 0);
    }

    // ---- Epilogue: rs += x_hat * (y + w1), x_hat bf16 from As ----
    float rs[4][4];
#pragma unroll
    for (int mi = 0; mi < 4; ++mi)
#pragma unroll
        for (int reg = 0; reg < 4; ++reg) rs[mi][reg] = 0.f;

#pragma unroll
    for (int ni = 0; ni < 8; ++ni) {
        const int gc = wave * 128 + ni * 16 + l16;
        const float w1v = w1[gc];
#pragma unroll
        for (int mi = 0; mi < 4; ++mi)
#pragma unroll
            for (int reg = 0; reg < 4; ++reg) {
                const int row = mi * 16 + quad * 4 + reg;
                const int adr = row * N_FEAT +
                                ((((gc >> 3) ^ (row & 7)) << 3) | (gc & 7));
                rs[mi][reg] = fmaf(bf16_to_f(As[adr]), acc[mi][ni][reg] + w1v,
                                   rs[mi][reg]);
            }
    }

    // ---- reduce over l16; combine 4 wave col-partials; bias + sigmoid ----
#pragma unroll
    for (int mi = 0; mi < 4; ++mi)
#pragma unroll
        for (int reg = 0; reg < 4; ++reg) {
            float r = rs[mi][reg];
#pragma unroll
            for (int off = 1; off < 16; off <<= 1)
                r += __shfl_xor(r, off, 16);
            if (l16 == 0)
                part[wave][mi * 16 + quad * 4 + reg] = r;
        }
    __syncthreads();

    if (tid < BM) {
        const float t = part[0][tid] + part[1][tid] + part[2][tid] + part[3][tid]
                        + bvec[0];
        out[row0 + tid] = 1.0f / (1.0f + expf(-t));
    }
}

extern "C" void kernel_launch(void* const* d_in, const int* in_sizes, int n_in,
                              void* d_out, int out_size, void* d_ws, size_t ws_size,
                              hipStream_t stream) {
    const float* X   = (const float*)d_in[0];   // 32768 x 512
    const float* w1  = (const float*)d_in[1];   // 512
    const float* b   = (const float*)d_in[2];   // 1
    const float* v   = (const float*)d_in[3];   // 512 x 30 x 40
    const int*   f2f = (const int*)d_in[4];     // 512
    float* out = (float*)d_out;                 // 32768

    unsigned short* W16 = (unsigned short*)d_ws;                  // 512 KB
    float*          vT  = (float*)((char*)d_ws + (1u << 20));     // 2.4 MB
    unsigned short* img = (unsigned short*)((char*)d_ws + (4u << 20)); // 512 KB

    transpose_v<<<FK, 256, 0, stream>>>(v, vT);
    build_w16<<<N_FEAT, 256, 0, stream>>>(v, vT, f2f, W16);
    retile_w<<<B_ROWS * N_FEAT / (256 * 64), 256, 0, stream>>>(W16, img);
    ffm_fused<<<B_ROWS / BM, 256, 0, stream>>>(X, img, w1, b, out);
}